// Round 4
// baseline (18.890 us; speedup 1.0000x reference)
//
#include <hip/hip_runtime.h>

// LPC residual, round 3b: 16 lanes/frame, 4 frames/wave, 4 waves/block.
// 8000 waves (7.8/SIMD) for latency hiding. DPP row_ror all-reduce (pure
// VALU, no LDS shuffles) -- ctrl as template param (must be immediate).
// ext_vector register windows (no scratch risk). Wave-private LDS staging
// -> no __syncthreads.

typedef float f32x2 __attribute__((ext_vector_type(2)));

#define FS 160
#define ORD 16
#define FPW 4            // frames per wave (16 lanes each)
#define WPB 4            // waves per block
#define FPB (FPW * WPB)  // 16 frames per block
#define SLOT 196         // 16 front pad + 160 + 16 back pad + 4 stagger
#define CHUNK 10         // t-positions per lane

// v += value rotated within the 16-lane DPP row (row_ror:n -> ctrl 0x120+n)
template <int CTRL>
__device__ __forceinline__ float rotadd(float v) {
    int p = __builtin_amdgcn_update_dpp(0, __builtin_bit_cast(int, v),
                                        CTRL, 0xF, 0xF, false);
    return v + __builtin_bit_cast(float, p);
}

__global__ __launch_bounds__(256, 6) void lpc_kernel(const float* __restrict__ x,
                                                     float* __restrict__ out,
                                                     int nframes) {
    __shared__ float sf[WPB * FPW * SLOT];  // 12544 B
    const int tid = threadIdx.x;
    const int wv = tid >> 6;
    const int lane = tid & 63;
    const int g = lane >> 4;   // frame within wave == DPP row
    const int li = lane & 15;  // lane within frame group
    const int wframe0 = (blockIdx.x * WPB + wv) * FPW;
    if (wframe0 >= nframes) return;  // 32000 % 16 == 0 -> full waves only
    float* s = sf + wv * FPW * SLOT;

    // ---- stage 4 frames (640 floats = 160 float4 per wave) ----
    const float4* xin = (const float4*)(x + (size_t)wframe0 * FS);
#pragma unroll
    for (int c = 0; c < 3; ++c) {
        unsigned i = (unsigned)lane + 64u * c;
        if (c < 2 || i < 160u) {
            float4 v = xin[i];
            unsigned f = i / 40u;            // frame 0..3
            unsigned p = 4u * i - f * 160u;  // position within frame
            *(float4*)(s + f * SLOT + 16 + p) = v;
        }
    }
    // ---- zero pads: per frame, front [0,16) and back [176,192) ----
#pragma unroll
    for (int c = 0; c < 2; ++c) {
        int z = lane + 64 * c;  // 0..127 = 4 frames x 32 pad slots
        int f = z >> 5, q = z & 31;
        s[f * SLOT + (q < 16 ? q : q + 160)] = 0.0f;
    }
    // LDS region is wave-private: same-wave lgkmcnt ordering suffices, no barrier.

    const float* fb = s + g * SLOT;

    // ---- autocorr: lane covers t in [10*li, 10*li+10), window [c, c+26) ----
    f32x2 w2[13];
    {
        const float* wa = fb + 16 + CHUNK * li;  // 8B-aligned
#pragma unroll
        for (int m = 0; m < 13; ++m) w2[m] = *(const f32x2*)(wa + 2 * m);
    }
#define W(m) (w2[(m) >> 1][(m) & 1])
    float r[ORD + 1];
#pragma unroll
    for (int j = 0; j <= ORD; ++j) {
        float p = 0.0f;
#pragma unroll
        for (int m = 0; m < CHUNK; ++m) p = fmaf(W(m), W(m + j), p);
        // all-reduce across the 16-lane row: rotates 1,2,4,8 (pure VALU)
        p = rotadd<0x121>(p);
        p = rotadd<0x122>(p);
        p = rotadd<0x124>(p);
        p = rotadd<0x128>(p);
        r[j] = p;
    }

    // ---- Levinson-Durbin (redundant across the 16 lanes of the group) ----
    float a[ORD + 1], tmp[ORD + 1];
    a[0] = 1.0f;
#pragma unroll
    for (int j = 1; j <= ORD; ++j) a[j] = 0.0f;
    float e = r[0];
#pragma unroll
    for (int i = 1; i <= ORD; ++i) {
        float s0 = 0.0f, s1 = 0.0f;  // split accumulators halve the dep chain
#pragma unroll
        for (int m = 1; m < i; ++m) {
            if (m & 1) s0 = fmaf(a[m], r[i - m], s0);
            else       s1 = fmaf(a[m], r[i - m], s1);
        }
        float k = (r[i] - s0 - s1) * __builtin_amdgcn_rcpf(e);
#pragma unroll
        for (int m = 1; m < i; ++m) tmp[m] = fmaf(-k, a[i - m], a[m]);
#pragma unroll
        for (int m = 1; m < i; ++m) a[m] = tmp[m];
        a[i] = k;
        e = e * (1.0f - k * k);
    }

    // ---- FIR: window [c-16, c+10) includes front pad ----
    f32x2 v2[13];
    {
        const float* vb = fb + CHUNK * li;  // 8B-aligned
#pragma unroll
        for (int m = 0; m < 13; ++m) v2[m] = *(const f32x2*)(vb + 2 * m);
    }
#define V(m) (v2[(m) >> 1][(m) & 1])
    float* op = out + (size_t)(wframe0 + g) * FS + CHUNK * li;
#pragma unroll
    for (int q = 0; q < 5; ++q) {
        f32x2 o;
#pragma unroll
        for (int u = 0; u < 2; ++u) {
            int t = 2 * q + u;
            float acc = 0.0f;
#pragma unroll
            for (int j = 0; j <= ORD; ++j) acc = fmaf(a[j], V(16 + t - j), acc);
            o[u] = acc;
        }
        *(f32x2*)(op + 2 * q) = o;
    }
}

extern "C" void kernel_launch(void* const* d_in, const int* in_sizes, int n_in,
                              void* d_out, int out_size, void* d_ws, size_t ws_size,
                              hipStream_t stream) {
    const float* x = (const float*)d_in[0];
    float* out = (float*)d_out;
    const int total = in_sizes[0];                 // 5,120,000
    const int nframes = total / FS;                // 32,000
    const int blocks = (nframes + FPB - 1) / FPB;  // 2,000
    lpc_kernel<<<blocks, 256, 0, stream>>>(x, out, nframes);
}